// Round 4
// baseline (988.911 us; speedup 1.0000x reference)
//
#include <hip/hip_runtime.h>

#define HID 32
#define BN_EPS 1e-5f
#define NBMAX 512
#define BSHIFT 9
#define SCAT_CH 8192
#define FSTRIDE 10240
#define FCAP 10240

static __device__ __forceinline__ int lbound(const int* a, int n, int key) {
    int lo = 0, hi = n;
    while (lo < hi) { int m = (lo + hi) >> 1; if (a[m] < key) lo = m + 1; else hi = m; }
    return lo;
}

static __device__ __forceinline__ unsigned packbf2(float a, float b) {
    unsigned ua = __float_as_uint(a), ub = __float_as_uint(b);
    ua = (ua + 0x7fffu + ((ua >> 16) & 1u)) >> 16;
    ub = (ub + 0x7fffu + ((ub >> 16) & 1u)) & 0xffff0000u;
    return ua | ub;
}
static __device__ __forceinline__ float lo_bf(unsigned v) { return __uint_as_float(v << 16); }
static __device__ __forceinline__ float hi_bf(unsigned v) { return __uint_as_float(v & 0xffff0000u); }

static __device__ __forceinline__ void addu4(float* a, uint4 v) {
    a[0] += lo_bf(v.x); a[1] += hi_bf(v.x);
    a[2] += lo_bf(v.y); a[3] += hi_bf(v.y);
    a[4] += lo_bf(v.z); a[5] += hi_bf(v.z);
    a[6] += lo_bf(v.w); a[7] += hi_bf(v.w);
}

// ---------------- bucketed CSR build (no count pass; fixed-stride buckets) ----------------
__global__ void __launch_bounds__(256) k_bscatter(const int* __restrict__ ei,
                                                  int* __restrict__ gcur,
                                                  int* __restrict__ pairs, int E, int NB) {
    __shared__ int h[NBMAX];
    __shared__ int lb[NBMAX];
    int t = threadIdx.x;
    int c0 = blockIdx.x * SCAT_CH;
    int end = min(c0 + SCAT_CH, E);
    for (int i = t; i < NBMAX; i += 256) h[i] = 0;
    __syncthreads();
    for (int i = c0 + t; i < end; i += 256)
        atomicAdd(&h[ei[E + i] >> BSHIFT], 1);
    __syncthreads();
    for (int b = t; b < NB; b += 256) {
        int c = h[b];
        lb[b] = c ? atomicAdd(&gcur[b], c) : 0;
        h[b] = 0;
    }
    __syncthreads();
    for (int i = c0 + t; i < end; i += 256) {
        int src = ei[i], d = ei[E + i];
        int bkt = d >> BSHIFT;
        int r = atomicAdd(&h[bkt], 1);
        pairs[bkt * FSTRIDE + lb[bkt] + r] = src | ((d & 511) << 18);
    }
}

__global__ void __launch_bounds__(512) k_bscan(const int* __restrict__ gcur,
                                               int* __restrict__ bbase,
                                               int* __restrict__ rowstart,
                                               int N, int E, int NB) {
    __shared__ int s[512];
    int t = threadIdx.x;
    int v = (t < NB) ? gcur[t] : 0;
    s[t] = v; __syncthreads();
    for (int off = 1; off < 512; off <<= 1) {
        int u = (t >= off) ? s[t - off] : 0; __syncthreads();
        s[t] += u; __syncthreads();
    }
    int excl = s[t] - v;
    if (t < NB) bbase[t] = excl;
    if (t == NB - 1) bbase[NB] = s[t];
    if (t == 0) rowstart[N] = E;
}

__global__ void __launch_bounds__(512) k_bfinal(const int* __restrict__ pairs,
                                                const int* __restrict__ bbase,
                                                const int* __restrict__ gcur,
                                                int* __restrict__ rowstart,
                                                int* __restrict__ csr, int N) {
    __shared__ int h[512];
    __shared__ int sc[512];
    __shared__ int loc[FCAP];
    int t = threadIdx.x;
    int b = blockIdx.x;
    int base = bbase[b];
    int cnt = gcur[b];
    const int* bp = pairs + (size_t)b * FSTRIDE;
    h[t] = 0;
    __syncthreads();
    for (int i = t; i < cnt; i += 512) atomicAdd(&h[bp[i] >> 18], 1);
    __syncthreads();
    int v = h[t];
    sc[t] = v; __syncthreads();
    for (int off = 1; off < 512; off <<= 1) {
        int u = (t >= off) ? sc[t - off] : 0; __syncthreads();
        sc[t] += u; __syncthreads();
    }
    int excl = sc[t] - v;
    int node = b * 512 + t;
    if (node < N) rowstart[node] = base + excl;
    h[t] = excl;
    __syncthreads();
    bool fit = (cnt <= FCAP);
    for (int i = t; i < cnt; i += 512) {
        int p = bp[i];
        int r = atomicAdd(&h[p >> 18], 1);
        int src = p & 0x3ffff;
        if (fit) loc[r] = src; else csr[base + r] = src;
    }
    __syncthreads();
    if (fit)
        for (int i = t; i < cnt; i += 512) csr[base + i] = loc[i];
}

// ---------------- GIN layers ----------------
// layer1: Ub = bf16(x @ W1)  (78 -> 32)
__global__ void __launch_bounds__(256) k_A1(const float* __restrict__ x,
                                            const float* __restrict__ W,
                                            unsigned* __restrict__ Ub, int N) {
    __shared__ float xl[64 * 79];
    __shared__ float wl[78 * 33];
    int t = threadIdx.x;
    int n0 = blockIdx.x * 64;
    for (int idx = t; idx < 78 * 32; idx += 256)
        wl[(idx >> 5) * 33 + (idx & 31)] = W[idx];
    long base = (long)n0 * 78;
    for (int idx = t; idx < 64 * 78; idx += 256) {
        long g = base + idx;
        xl[(idx / 78) * 79 + (idx % 78)] = (g < (long)N * 78) ? x[g] : 0.f;
    }
    __syncthreads();
    int jp = t & 15, rg = t >> 4;
    for (int rep = 0; rep < 4; rep++) {
        int n = rg + 16 * rep;
        int node = n0 + n;
        if (node >= N) break;
        float a0 = 0.f, a1 = 0.f;
        #pragma unroll
        for (int k = 0; k < 78; k++) {
            float xv = xl[n * 79 + k];
            a0 += xv * wl[k * 33 + 2 * jp];
            a1 += xv * wl[k * 33 + 2 * jp + 1];
        }
        Ub[(size_t)node * 16 + jp] = packbf2(a0, a1);
    }
}

// layers 2..5: Ub = bf16((X*a + c) @ W1), BN folded
__global__ void __launch_bounds__(256) k_A(const float* __restrict__ X,
                                           const float* __restrict__ W,
                                           const float* __restrict__ slot,
                                           unsigned* __restrict__ Ub, int N) {
    __shared__ float zl[128 * 33];
    __shared__ float ws[32 * 33];
    __shared__ float cw[32];
    int t = threadIdx.x;
    int n0 = blockIdx.x * 128;
    for (int idx = t; idx < 1024; idx += 256) {
        int k = idx >> 5, j = idx & 31;
        ws[k * 33 + j] = slot[512 + k] * W[idx];
    }
    if (t < 32) {
        float acc = 0.f;
        for (int k = 0; k < 32; k++) acc += slot[544 + k] * W[k * 32 + t];
        cw[t] = acc;
    }
    for (int idx = t; idx < 128 * 32; idx += 256) {
        long g = (long)n0 * 32 + idx;
        zl[(idx >> 5) * 33 + (idx & 31)] = (g < (long)N * 32) ? X[g] : 0.f;
    }
    __syncthreads();
    int jp = t & 15, rg = t >> 4;
    for (int rep = 0; rep < 8; rep++) {
        int n = rg + 16 * rep;
        int node = n0 + n;
        if (node >= N) break;
        float a0 = cw[2 * jp], a1 = cw[2 * jp + 1];
        #pragma unroll
        for (int k = 0; k < 32; k++) {
            float zv = zl[n * 33 + k];
            a0 += zv * ws[k * 33 + 2 * jp];
            a1 += zv * ws[k * 33 + 2 * jp + 1];
        }
        Ub[(size_t)node * 16 + jp] = packbf2(a0, a1);
    }
}

// fused: gather-sum(bf16 U rows) -> relu(+b1) -> @W2+b2 -> relu -> X, + stats
// 4-lane groups, uint4 row loads, 2-edge unroll for MLP
__global__ void __launch_bounds__(256) k_BCS(const uint4* __restrict__ Ub4,
                                             const int* __restrict__ rowstart,
                                             const int* __restrict__ csr,
                                             const float* __restrict__ b1,
                                             const float* __restrict__ W2,
                                             const float* __restrict__ b2,
                                             float* __restrict__ X,
                                             float* __restrict__ slot, int N) {
    __shared__ float ws[32 * 33];
    __shared__ float tl[64 * 33];
    __shared__ float redS[8][33];
    __shared__ float redQ[8][33];
    int t = threadIdx.x;
    for (int idx = t; idx < 1024; idx += 256)
        ws[(idx >> 5) * 33 + (idx & 31)] = W2[idx];

    int g = t >> 2, l = t & 3;
    int node = blockIdx.x * 64 + g;
    bool act = (node < N);
    int s0 = 0, s1 = 0;
    if (act) { s0 = rowstart[node]; s1 = rowstart[node + 1]; }
    float a[8] = {0.f, 0.f, 0.f, 0.f, 0.f, 0.f, 0.f, 0.f};
    if (act) addu4(a, Ub4[(size_t)node * 4 + l]);
    int e = s0;
    for (; e + 1 < s1; e += 2) {
        int sa = csr[e], sb = csr[e + 1];
        uint4 va = Ub4[(size_t)sa * 4 + l];
        uint4 vb = Ub4[(size_t)sb * 4 + l];
        addu4(a, va);
        addu4(a, vb);
    }
    if (e < s1) addu4(a, Ub4[(size_t)csr[e] * 4 + l]);

    int f0 = 8 * l;
    #pragma unroll
    for (int i = 0; i < 8; i++)
        tl[g * 33 + f0 + i] = fmaxf(a[i] + b1[f0 + i], 0.f);
    __syncthreads();

    int j = t & 31, rg2 = t >> 5;
    float ps = 0.f, pq = 0.f;
    for (int rep = 0; rep < 8; rep++) {
        int n = rg2 + 8 * rep;
        int nod2 = blockIdx.x * 64 + n;
        float acc = b2[j];
        #pragma unroll
        for (int k = 0; k < 32; k++) acc += tl[n * 33 + k] * ws[k * 33 + j];
        float xv = fmaxf(acc, 0.f);
        if (nod2 < N) {
            X[(size_t)nod2 * 32 + j] = xv;
            ps += xv; pq += xv * xv;
        }
    }
    redS[rg2][j] = ps; redQ[rg2][j] = pq;
    __syncthreads();
    if (t < 32) {
        float s = 0.f, q = 0.f;
        #pragma unroll
        for (int r = 0; r < 8; r++) { s += redS[r][t]; q += redQ[r][t]; }
        int rep = blockIdx.x & 7;
        atomicAdd(&slot[rep * 64 + t], s);
        atomicAdd(&slot[rep * 64 + 32 + t], q);
    }
}

// finalize BN affine: a -> slot[512..543], c -> slot[544..575]
__global__ void k_fin(float* __restrict__ slot, const float* __restrict__ gamma,
                      const float* __restrict__ beta, int N) {
    int j = threadIdx.x;
    if (j < 32) {
        float s = 0.f, q = 0.f;
        for (int r = 0; r < 8; r++) { s += slot[r * 64 + j]; q += slot[r * 64 + 32 + j]; }
        float mu = s / (float)N;
        float var = q / (float)N - mu * mu;
        float a = gamma[j] * rsqrtf(var + BN_EPS);
        slot[512 + j] = a;
        slot[544 + j] = beta[j] - mu * a;
    }
}

// pool z5 per graph, fold BN, xd = relu(pooled@fcxd_w+b) -> xc[:,0:128]
__global__ void __launch_bounds__(128) k_pool(const float* __restrict__ X,
                                              const int* __restrict__ batch,
                                              const float* __restrict__ slot,
                                              const float* __restrict__ fw,
                                              const float* __restrict__ fb,
                                              float* __restrict__ xc, int N) {
    __shared__ float red[4][32];
    __shared__ float pv[32];
    int g = blockIdx.x, t = threadIdx.x;
    int lo = lbound(batch, N, g);
    int hi = lbound(batch, N, g + 1);
    int j = t & 31, rs = t >> 5;
    float ps = 0.f;
    for (int i = lo + rs; i < hi; i += 4) ps += X[(size_t)i * 32 + j];
    red[rs][j] = ps; __syncthreads();
    if (t < 32) {
        float s = red[0][t] + red[1][t] + red[2][t] + red[3][t];
        pv[t] = s * slot[512 + t] + (float)(hi - lo) * slot[544 + t];
    }
    __syncthreads();
    float acc = fb[t];
    for (int k = 0; k < 32; k++) acc += pv[k] * fw[k * 128 + t];
    xc[g * 256 + t] = fmaxf(acc, 0.f);
}

// ---------------- protein branch ----------------
// per (v,o): all 8 k-offsets in one pass over the o-slice of fcxt
__global__ void __launch_bounds__(128) k_F2(const float* __restrict__ Emb,
                                            const float* __restrict__ fcxt,
                                            float* __restrict__ F) {
    __shared__ float er[128];
    int bid = blockIdx.x;
    int v = bid >> 5, o = bid & 31;
    int t = threadIdx.x;
    er[t] = Emb[v * 128 + t];
    __syncthreads();
    float acc[8] = {0.f, 0.f, 0.f, 0.f, 0.f, 0.f, 0.f, 0.f};
    for (int p = 0; p < 121; p++) {
        float fv = fcxt[(o * 121 + p) * 128 + t];
        #pragma unroll
        for (int k = 0; k < 8; k++) acc[k] += er[p + k] * fv;
    }
    #pragma unroll
    for (int k = 0; k < 8; k++)
        F[((size_t)v * 256 + o * 8 + k) * 128 + t] = acc[k];
}

__global__ void __launch_bounds__(128) k_cb(const float* __restrict__ fcxt,
                                            const float* __restrict__ fb,
                                            const float* __restrict__ cb,
                                            float* __restrict__ cbias) {
    int o = blockIdx.x, t = threadIdx.x;
    float acc = 0.f;
    for (int p = 0; p < 121; p++) acc += fcxt[(o * 121 + p) * 128 + t];
    float val = cb[o] * acc;
    if (o == 0) val += fb[t];
    atomicAdd(&cbias[t], val);
}

// transpose conv_w [o][c][k] -> wt[ok=o*8+k][c]
__global__ void __launch_bounds__(256) k_wT(const float* __restrict__ cw,
                                            float* __restrict__ wt) {
    int ok = blockIdx.x;
    int o = ok >> 3, kk = ok & 7;
    for (int c = threadIdx.x; c < 1000; c += 256)
        wt[ok * 1000 + c] = cw[(o * 1000 + c) * 8 + kk];
}

// Dm_bf[c][v][j-pairs] = bf16( sum_ok wt[ok][c] * F[v][ok][j] )
__global__ void __launch_bounds__(256) k_D2(const float* __restrict__ wt,
                                            const float* __restrict__ F,
                                            unsigned* __restrict__ Dmb) {
    __shared__ float Fl[32][128];
    __shared__ float Wl[32][64];
    int v = blockIdx.y;
    int c0 = blockIdx.x * 64;
    int t = threadIdx.x;
    int jg = t & 31, j0 = jg * 4;
    int cg = t >> 5;
    float4 acc[8];
    #pragma unroll
    for (int i = 0; i < 8; i++) acc[i] = make_float4(0.f, 0.f, 0.f, 0.f);
    for (int chunk = 0; chunk < 8; chunk++) {
        int k0 = chunk * 32;
        __syncthreads();
        for (int idx = t; idx < 4096; idx += 256) {
            int k = idx >> 7, j = idx & 127;
            Fl[k][j] = F[((size_t)v * 256 + k0 + k) * 128 + j];
        }
        for (int idx = t; idx < 2048; idx += 256) {
            int k = idx >> 6, c = idx & 63;
            Wl[k][c] = (c0 + c < 1000) ? wt[(k0 + k) * 1000 + c0 + c] : 0.f;
        }
        __syncthreads();
        for (int k = 0; k < 32; k++) {
            float4 fv = *(const float4*)&Fl[k][j0];
            #pragma unroll
            for (int ci = 0; ci < 8; ci++) {
                float wv = Wl[k][cg * 8 + ci];
                acc[ci].x += wv * fv.x;
                acc[ci].y += wv * fv.y;
                acc[ci].z += wv * fv.z;
                acc[ci].w += wv * fv.w;
            }
        }
    }
    #pragma unroll
    for (int ci = 0; ci < 8; ci++) {
        int c = c0 + cg * 8 + ci;
        if (c < 1000) {
            uint2 pk;
            pk.x = packbf2(acc[ci].x, acc[ci].y);
            pk.y = packbf2(acc[ci].z, acc[ci].w);
            *(uint2*)&Dmb[((size_t)c * 26 + v) * 64 + jg * 2] = pk;
        }
    }
}

// xt init: xc[:,128:256] = cbias
__global__ void __launch_bounds__(128) k_xtinit(const float* __restrict__ cbias,
                                                float* __restrict__ xc) {
    xc[blockIdx.x * 256 + 128 + threadIdx.x] = cbias[threadIdx.x];
}

// xt accumulate: c-chunked, register-tiled, bf16 Dm gathers, atomicAdd outputs
// grid: (8 b-groups of 128 graphs) x (40 c-chunks of 25)
__global__ void __launch_bounds__(256) k_xt2(const int* __restrict__ target,
                                             const uint4* __restrict__ Dm4,
                                             float* __restrict__ xc) {
    __shared__ int tl[128 * 25];
    int t = threadIdx.x;
    int b0 = blockIdx.x * 128;
    int c0 = blockIdx.y * 25;
    for (int idx = t; idx < 3200; idx += 256) {
        int g = idx / 25, ci = idx - g * 25;
        tl[idx] = target[(size_t)(b0 + g) * 1000 + c0 + ci];
    }
    __syncthreads();
    int jg = t & 15;            // 16 j-groups x uint4 = 8 features each
    int gg = t >> 4;            // 16 g-groups x 8 graphs
    float acc[8][8];
    #pragma unroll
    for (int gi = 0; gi < 8; gi++)
        #pragma unroll
        for (int fi = 0; fi < 8; fi++) acc[gi][fi] = 0.f;
    for (int ci = 0; ci < 25; ci++) {
        int cc = c0 + ci;
        #pragma unroll
        for (int gi = 0; gi < 8; gi++) {
            int v = tl[(gg * 8 + gi) * 25 + ci];
            uint4 d = Dm4[((size_t)cc * 26 + v) * 16 + jg];
            acc[gi][0] += lo_bf(d.x); acc[gi][1] += hi_bf(d.x);
            acc[gi][2] += lo_bf(d.y); acc[gi][3] += hi_bf(d.y);
            acc[gi][4] += lo_bf(d.z); acc[gi][5] += hi_bf(d.z);
            acc[gi][6] += lo_bf(d.w); acc[gi][7] += hi_bf(d.w);
        }
    }
    #pragma unroll
    for (int gi = 0; gi < 8; gi++) {
        int b = b0 + gg * 8 + gi;
        #pragma unroll
        for (int fi = 0; fi < 8; fi++)
            atomicAdd(&xc[(size_t)b * 256 + 128 + jg * 8 + fi], acc[gi][fi]);
    }
}

// ---------------- head ----------------
__global__ void __launch_bounds__(256) k_fc1(const float* __restrict__ xc,
                                             const float* __restrict__ w,
                                             const float* __restrict__ bias,
                                             float* __restrict__ y1) {
    __shared__ float xl[16 * 256];
    int t = threadIdx.x;
    int q0 = blockIdx.x * 256, b0 = blockIdx.y * 16;
    for (int idx = t; idx < 4096; idx += 256) xl[idx] = xc[b0 * 256 + idx];
    __syncthreads();
    int ql = t & 63, q = q0 + ql * 4;
    int bg = t >> 6;
    float4 bv = *(const float4*)&bias[q];
    float4 acc0 = bv, acc1 = bv, acc2 = bv, acc3 = bv;
    const float* xr = &xl[bg * 4 * 256];
    #pragma unroll 4
    for (int k = 0; k < 256; k++) {
        float4 wv = *(const float4*)&w[k * 1024 + q];
        float x0 = xr[k], x1 = xr[256 + k], x2 = xr[512 + k], x3 = xr[768 + k];
        acc0.x += x0 * wv.x; acc0.y += x0 * wv.y; acc0.z += x0 * wv.z; acc0.w += x0 * wv.w;
        acc1.x += x1 * wv.x; acc1.y += x1 * wv.y; acc1.z += x1 * wv.z; acc1.w += x1 * wv.w;
        acc2.x += x2 * wv.x; acc2.y += x2 * wv.y; acc2.z += x2 * wv.z; acc2.w += x2 * wv.w;
        acc3.x += x3 * wv.x; acc3.y += x3 * wv.y; acc3.z += x3 * wv.z; acc3.w += x3 * wv.w;
    }
    int b = b0 + bg * 4;
    float4 r;
    r.x = fmaxf(acc0.x, 0.f); r.y = fmaxf(acc0.y, 0.f); r.z = fmaxf(acc0.z, 0.f); r.w = fmaxf(acc0.w, 0.f);
    *(float4*)&y1[(size_t)b * 1024 + q] = r;
    r.x = fmaxf(acc1.x, 0.f); r.y = fmaxf(acc1.y, 0.f); r.z = fmaxf(acc1.z, 0.f); r.w = fmaxf(acc1.w, 0.f);
    *(float4*)&y1[(size_t)(b + 1) * 1024 + q] = r;
    r.x = fmaxf(acc2.x, 0.f); r.y = fmaxf(acc2.y, 0.f); r.z = fmaxf(acc2.z, 0.f); r.w = fmaxf(acc2.w, 0.f);
    *(float4*)&y1[(size_t)(b + 2) * 1024 + q] = r;
    r.x = fmaxf(acc3.x, 0.f); r.y = fmaxf(acc3.y, 0.f); r.z = fmaxf(acc3.z, 0.f); r.w = fmaxf(acc3.w, 0.f);
    *(float4*)&y1[(size_t)(b + 3) * 1024 + q] = r;
}

__global__ void k_wcomb(const float* __restrict__ fc2w, const float* __restrict__ fc2b,
                        const float* __restrict__ ow, const float* __restrict__ ob,
                        float* __restrict__ wc) {
    int p = blockIdx.x * 256 + threadIdx.x;
    float acc = 0.f;
    for (int q = 0; q < 256; q++) acc += fc2w[p * 256 + q] * ow[q];
    wc[p] = acc;
    if (p == 0) {
        float bc = ob[0];
        for (int q = 0; q < 256; q++) bc += fc2b[q] * ow[q];
        wc[1024] = bc;
    }
}

__global__ void __launch_bounds__(256) k_out(const float* __restrict__ y1,
                                             const float* __restrict__ wc,
                                             float* __restrict__ out) {
    __shared__ float r[256];
    int b = blockIdx.x, t = threadIdx.x;
    float acc = 0.f;
    for (int p = t; p < 1024; p += 256) acc += y1[b * 1024 + p] * wc[p];
    r[t] = acc; __syncthreads();
    for (int off = 128; off > 0; off >>= 1) {
        if (t < off) r[t] += r[t + off];
        __syncthreads();
    }
    if (t == 0) out[b] = r[0] + wc[1024];
}

extern "C" void kernel_launch(void* const* d_in, const int* in_sizes, int n_in,
                              void* d_out, int out_size, void* d_ws, size_t ws_size,
                              hipStream_t stream) {
    const float* x     = (const float*)d_in[0];
    const int*   ei    = (const int*)d_in[1];
    const int*   batch = (const int*)d_in[2];
    const int*   targ  = (const int*)d_in[3];
    const float* g1w1  = (const float*)d_in[4];
    const float* g1b1  = (const float*)d_in[5];
    const float* g1w2  = (const float*)d_in[6];
    const float* g1b2  = (const float*)d_in[7];
    const float* gW1   = (const float*)d_in[8];
    const float* gb1   = (const float*)d_in[9];
    const float* gW2   = (const float*)d_in[10];
    const float* gb2   = (const float*)d_in[11];
    const float* gam   = (const float*)d_in[12];
    const float* bet   = (const float*)d_in[13];
    const float* fcxdw = (const float*)d_in[14];
    const float* fcxdb = (const float*)d_in[15];
    const float* emb   = (const float*)d_in[16];
    const float* convw = (const float*)d_in[17];
    const float* convb = (const float*)d_in[18];
    const float* fcxtw = (const float*)d_in[19];
    const float* fcxtb = (const float*)d_in[20];
    const float* fc1w  = (const float*)d_in[21];
    const float* fc1b  = (const float*)d_in[22];
    const float* fc2w  = (const float*)d_in[23];
    const float* fc2b  = (const float*)d_in[24];
    const float* outw  = (const float*)d_in[25];
    const float* outb  = (const float*)d_in[26];

    int N = in_sizes[2];
    int E = in_sizes[1] / 2;
    int B = in_sizes[3] / 1000;
    int NB = (N + 511) >> BSHIFT;

    char* ws = (char*)d_ws;
    size_t off = 0;
    auto alloc = [&](size_t bytes) -> void* {
        void* p = ws + off;
        off += (bytes + 255) & ~(size_t)255;
        return p;
    };
    int*   rowstart = (int*)alloc((size_t)(N + 1) * 4);
    int*   bbase    = (int*)alloc((NBMAX + 1) * 4);
    int*   gcur     = (int*)alloc(NBMAX * 4);
    int*   csr      = (int*)alloc((size_t)E * 4);
    // pairs (NB*FSTRIDE*4 = 16 MB) aliases X (N*32*4 = 25.6 MB): pairs dead before first X write
    float* X        = (float*)alloc((size_t)N * 32 * 4);
    int*   pairs    = (int*)X;
    unsigned* Ub    = (unsigned*)alloc((size_t)N * 16 * 4);
    float* stats    = (float*)alloc((size_t)5 * 640 * 4);
    float* xc       = (float*)alloc((size_t)B * 256 * 4);
    float* Fb       = (float*)alloc((size_t)26 * 256 * 128 * 4);
    unsigned* Dmb   = (unsigned*)alloc((size_t)1000 * 26 * 64 * 4);
    float* wt       = (float*)alloc((size_t)256 * 1000 * 4);
    float* cbias    = (float*)alloc(128 * 4);
    float* y1       = (float*)alloc((size_t)B * 1024 * 4);
    float* wc       = (float*)alloc(1025 * 4);

    hipMemsetAsync(gcur, 0, NBMAX * 4, stream);
    hipMemsetAsync(stats, 0, (size_t)5 * 640 * 4, stream);
    hipMemsetAsync(cbias, 0, 128 * 4, stream);

    // CSR build
    k_bscatter<<<(E + SCAT_CH - 1) / SCAT_CH, 256, 0, stream>>>(ei, gcur, pairs, E, NB);
    k_bscan<<<1, 512, 0, stream>>>(gcur, bbase, rowstart, N, E, NB);
    k_bfinal<<<NB, 512, 0, stream>>>(pairs, bbase, gcur, rowstart, csr, N);

    // layer 1
    k_A1<<<(N + 63) / 64, 256, 0, stream>>>(x, g1w1, Ub, N);
    k_BCS<<<(N + 63) / 64, 256, 0, stream>>>((const uint4*)Ub, rowstart, csr,
                                             g1b1, g1w2, g1b2, X, stats, N);
    k_fin<<<1, 32, 0, stream>>>(stats, gam, bet, N);

    // layers 2..5
    for (int i = 0; i < 4; i++) {
        float* slotPrev = stats + (size_t)i * 640;
        float* slotCur  = stats + (size_t)(i + 1) * 640;
        k_A<<<(N + 127) / 128, 256, 0, stream>>>(X, gW1 + i * 1024, slotPrev, Ub, N);
        k_BCS<<<(N + 63) / 64, 256, 0, stream>>>((const uint4*)Ub, rowstart, csr,
                                                 gb1 + i * 32, gW2 + i * 1024,
                                                 gb2 + i * 32, X, slotCur, N);
        k_fin<<<1, 32, 0, stream>>>(slotCur, gam + (i + 1) * 32, bet + (i + 1) * 32, N);
    }

    // pooling + xd -> xc[:, 0:128]
    k_pool<<<B, 128, 0, stream>>>(X, batch, stats + 4 * 640, fcxdw, fcxdb, xc, N);

    // protein branch -> xc[:, 128:256]
    k_wT<<<256, 256, 0, stream>>>(convw, wt);
    k_F2<<<26 * 32, 128, 0, stream>>>(emb, fcxtw, Fb);
    k_cb<<<32, 128, 0, stream>>>(fcxtw, fcxtb, convb, cbias);
    k_xtinit<<<B, 128, 0, stream>>>(cbias, xc);
    dim3 gD(16, 26);
    k_D2<<<gD, 256, 0, stream>>>(wt, Fb, Dmb);
    dim3 gX(B / 128, 40);
    k_xt2<<<gX, 256, 0, stream>>>(targ, (const uint4*)Dmb, xc);

    // head
    dim3 g1(4, B / 16);
    k_fc1<<<g1, 256, 0, stream>>>(xc, fc1w, fc1b, y1);
    k_wcomb<<<4, 256, 0, stream>>>(fc2w, fc2b, outw, outb, wc);
    k_out<<<B, 256, 0, stream>>>(y1, wc, (float*)d_out);
}

// Round 5
// 799.630 us; speedup vs baseline: 1.2367x; 1.2367x over previous
//
#include <hip/hip_runtime.h>

#define HID 32
#define BN_EPS 1e-5f
#define NBMAX 512
#define BSHIFT 9
#define SCAT_CH 8192
#define FSTRIDE 10240
#define FCAP 10240

static __device__ __forceinline__ int lbound(const int* a, int n, int key) {
    int lo = 0, hi = n;
    while (lo < hi) { int m = (lo + hi) >> 1; if (a[m] < key) lo = m + 1; else hi = m; }
    return lo;
}

static __device__ __forceinline__ unsigned packbf2(float a, float b) {
    unsigned ua = __float_as_uint(a), ub = __float_as_uint(b);
    ua = (ua + 0x7fffu + ((ua >> 16) & 1u)) >> 16;
    ub = (ub + 0x7fffu + ((ub >> 16) & 1u)) & 0xffff0000u;
    return ua | ub;
}
static __device__ __forceinline__ float lo_bf(unsigned v) { return __uint_as_float(v << 16); }
static __device__ __forceinline__ float hi_bf(unsigned v) { return __uint_as_float(v & 0xffff0000u); }

static __device__ __forceinline__ void addu4(float* a, uint4 v) {
    a[0] += lo_bf(v.x); a[1] += hi_bf(v.x);
    a[2] += lo_bf(v.y); a[3] += hi_bf(v.y);
    a[4] += lo_bf(v.z); a[5] += hi_bf(v.z);
    a[6] += lo_bf(v.w); a[7] += hi_bf(v.w);
}

// ---------------- bucketed CSR build (no count pass; fixed-stride buckets) ----------------
__global__ void __launch_bounds__(256) k_bscatter(const int* __restrict__ ei,
                                                  int* __restrict__ gcur,
                                                  int* __restrict__ pairs, int E, int NB) {
    __shared__ int h[NBMAX];
    __shared__ int lb[NBMAX];
    int t = threadIdx.x;
    int c0 = blockIdx.x * SCAT_CH;
    int end = min(c0 + SCAT_CH, E);
    for (int i = t; i < NBMAX; i += 256) h[i] = 0;
    __syncthreads();
    for (int i = c0 + t; i < end; i += 256)
        atomicAdd(&h[ei[E + i] >> BSHIFT], 1);
    __syncthreads();
    for (int b = t; b < NB; b += 256) {
        int c = h[b];
        lb[b] = c ? atomicAdd(&gcur[b], c) : 0;
        h[b] = 0;
    }
    __syncthreads();
    for (int i = c0 + t; i < end; i += 256) {
        int src = ei[i], d = ei[E + i];
        int bkt = d >> BSHIFT;
        int r = atomicAdd(&h[bkt], 1);
        pairs[bkt * FSTRIDE + lb[bkt] + r] = src | ((d & 511) << 18);
    }
}

__global__ void __launch_bounds__(512) k_bscan(const int* __restrict__ gcur,
                                               int* __restrict__ bbase,
                                               int* __restrict__ rowstart,
                                               int N, int E, int NB) {
    __shared__ int s[512];
    int t = threadIdx.x;
    int v = (t < NB) ? gcur[t] : 0;
    s[t] = v; __syncthreads();
    for (int off = 1; off < 512; off <<= 1) {
        int u = (t >= off) ? s[t - off] : 0; __syncthreads();
        s[t] += u; __syncthreads();
    }
    int excl = s[t] - v;
    if (t < NB) bbase[t] = excl;
    if (t == NB - 1) bbase[NB] = s[t];
    if (t == 0) rowstart[N] = E;
}

__global__ void __launch_bounds__(512) k_bfinal(const int* __restrict__ pairs,
                                                const int* __restrict__ bbase,
                                                const int* __restrict__ gcur,
                                                int* __restrict__ rowstart,
                                                int* __restrict__ csr, int N) {
    __shared__ int h[512];
    __shared__ int sc[512];
    __shared__ int loc[FCAP];
    int t = threadIdx.x;
    int b = blockIdx.x;
    int base = bbase[b];
    int cnt = gcur[b];
    const int* bp = pairs + (size_t)b * FSTRIDE;
    h[t] = 0;
    __syncthreads();
    for (int i = t; i < cnt; i += 512) atomicAdd(&h[bp[i] >> 18], 1);
    __syncthreads();
    int v = h[t];
    sc[t] = v; __syncthreads();
    for (int off = 1; off < 512; off <<= 1) {
        int u = (t >= off) ? sc[t - off] : 0; __syncthreads();
        sc[t] += u; __syncthreads();
    }
    int excl = sc[t] - v;
    int node = b * 512 + t;
    if (node < N) rowstart[node] = base + excl;
    h[t] = excl;
    __syncthreads();
    bool fit = (cnt <= FCAP);
    for (int i = t; i < cnt; i += 512) {
        int p = bp[i];
        int r = atomicAdd(&h[p >> 18], 1);
        int src = p & 0x3ffff;
        if (fit) loc[r] = src; else csr[base + r] = src;
    }
    __syncthreads();
    if (fit)
        for (int i = t; i < cnt; i += 512) csr[base + i] = loc[i];
}

// ---------------- GIN layers ----------------
// layer1: Ub = bf16(x @ W1)  (78 -> 32)
__global__ void __launch_bounds__(256) k_A1(const float* __restrict__ x,
                                            const float* __restrict__ W,
                                            unsigned* __restrict__ Ub, int N) {
    __shared__ float xl[64 * 79];
    __shared__ float wl[78 * 33];
    int t = threadIdx.x;
    int n0 = blockIdx.x * 64;
    for (int idx = t; idx < 78 * 32; idx += 256)
        wl[(idx >> 5) * 33 + (idx & 31)] = W[idx];
    long base = (long)n0 * 78;
    for (int idx = t; idx < 64 * 78; idx += 256) {
        long g = base + idx;
        xl[(idx / 78) * 79 + (idx % 78)] = (g < (long)N * 78) ? x[g] : 0.f;
    }
    __syncthreads();
    int jp = t & 15, rg = t >> 4;
    for (int rep = 0; rep < 4; rep++) {
        int n = rg + 16 * rep;
        int node = n0 + n;
        if (node >= N) break;
        float a0 = 0.f, a1 = 0.f;
        #pragma unroll
        for (int k = 0; k < 78; k++) {
            float xv = xl[n * 79 + k];
            a0 += xv * wl[k * 33 + 2 * jp];
            a1 += xv * wl[k * 33 + 2 * jp + 1];
        }
        Ub[(size_t)node * 16 + jp] = packbf2(a0, a1);
    }
}

// layers 2..5: Ub = bf16((X*a + c) @ W1), BN folded
__global__ void __launch_bounds__(256) k_A(const float* __restrict__ X,
                                           const float* __restrict__ W,
                                           const float* __restrict__ slot,
                                           unsigned* __restrict__ Ub, int N) {
    __shared__ float zl[128 * 33];
    __shared__ float ws[32 * 33];
    __shared__ float cw[32];
    int t = threadIdx.x;
    int n0 = blockIdx.x * 128;
    for (int idx = t; idx < 1024; idx += 256) {
        int k = idx >> 5, j = idx & 31;
        ws[k * 33 + j] = slot[512 + k] * W[idx];
    }
    if (t < 32) {
        float acc = 0.f;
        for (int k = 0; k < 32; k++) acc += slot[544 + k] * W[k * 32 + t];
        cw[t] = acc;
    }
    for (int idx = t; idx < 128 * 32; idx += 256) {
        long g = (long)n0 * 32 + idx;
        zl[(idx >> 5) * 33 + (idx & 31)] = (g < (long)N * 32) ? X[g] : 0.f;
    }
    __syncthreads();
    int jp = t & 15, rg = t >> 4;
    for (int rep = 0; rep < 8; rep++) {
        int n = rg + 16 * rep;
        int node = n0 + n;
        if (node >= N) break;
        float a0 = cw[2 * jp], a1 = cw[2 * jp + 1];
        #pragma unroll
        for (int k = 0; k < 32; k++) {
            float zv = zl[n * 33 + k];
            a0 += zv * ws[k * 33 + 2 * jp];
            a1 += zv * ws[k * 33 + 2 * jp + 1];
        }
        Ub[(size_t)node * 16 + jp] = packbf2(a0, a1);
    }
}

// fused: gather-sum(bf16 U rows) -> relu(+b1) -> @W2+b2 -> relu -> X, + stats
__global__ void __launch_bounds__(256) k_BCS(const uint4* __restrict__ Ub4,
                                             const int* __restrict__ rowstart,
                                             const int* __restrict__ csr,
                                             const float* __restrict__ b1,
                                             const float* __restrict__ W2,
                                             const float* __restrict__ b2,
                                             float* __restrict__ X,
                                             float* __restrict__ slot, int N) {
    __shared__ float ws[32 * 33];
    __shared__ float tl[64 * 33];
    __shared__ float redS[8][33];
    __shared__ float redQ[8][33];
    int t = threadIdx.x;
    for (int idx = t; idx < 1024; idx += 256)
        ws[(idx >> 5) * 33 + (idx & 31)] = W2[idx];

    int g = t >> 2, l = t & 3;
    int node = blockIdx.x * 64 + g;
    bool act = (node < N);
    int s0 = 0, s1 = 0;
    if (act) { s0 = rowstart[node]; s1 = rowstart[node + 1]; }
    float a[8] = {0.f, 0.f, 0.f, 0.f, 0.f, 0.f, 0.f, 0.f};
    if (act) addu4(a, Ub4[(size_t)node * 4 + l]);
    int e = s0;
    for (; e + 1 < s1; e += 2) {
        int sa = csr[e], sb = csr[e + 1];
        uint4 va = Ub4[(size_t)sa * 4 + l];
        uint4 vb = Ub4[(size_t)sb * 4 + l];
        addu4(a, va);
        addu4(a, vb);
    }
    if (e < s1) addu4(a, Ub4[(size_t)csr[e] * 4 + l]);

    int f0 = 8 * l;
    #pragma unroll
    for (int i = 0; i < 8; i++)
        tl[g * 33 + f0 + i] = fmaxf(a[i] + b1[f0 + i], 0.f);
    __syncthreads();

    int j = t & 31, rg2 = t >> 5;
    float ps = 0.f, pq = 0.f;
    for (int rep = 0; rep < 8; rep++) {
        int n = rg2 + 8 * rep;
        int nod2 = blockIdx.x * 64 + n;
        float acc = b2[j];
        #pragma unroll
        for (int k = 0; k < 32; k++) acc += tl[n * 33 + k] * ws[k * 33 + j];
        float xv = fmaxf(acc, 0.f);
        if (nod2 < N) {
            X[(size_t)nod2 * 32 + j] = xv;
            ps += xv; pq += xv * xv;
        }
    }
    redS[rg2][j] = ps; redQ[rg2][j] = pq;
    __syncthreads();
    if (t < 32) {
        float s = 0.f, q = 0.f;
        #pragma unroll
        for (int r = 0; r < 8; r++) { s += redS[r][t]; q += redQ[r][t]; }
        int rep = blockIdx.x & 7;
        atomicAdd(&slot[rep * 64 + t], s);
        atomicAdd(&slot[rep * 64 + 32 + t], q);
    }
}

// finalize BN affine: a -> slot[512..543], c -> slot[544..575]
__global__ void k_fin(float* __restrict__ slot, const float* __restrict__ gamma,
                      const float* __restrict__ beta, int N) {
    int j = threadIdx.x;
    if (j < 32) {
        float s = 0.f, q = 0.f;
        for (int r = 0; r < 8; r++) { s += slot[r * 64 + j]; q += slot[r * 64 + 32 + j]; }
        float mu = s / (float)N;
        float var = q / (float)N - mu * mu;
        float a = gamma[j] * rsqrtf(var + BN_EPS);
        slot[512 + j] = a;
        slot[544 + j] = beta[j] - mu * a;
    }
}

// pool z5 per graph, fold BN, xd = relu(pooled@fcxd_w+b) -> xc[:,0:128]
__global__ void __launch_bounds__(128) k_pool(const float* __restrict__ X,
                                              const int* __restrict__ batch,
                                              const float* __restrict__ slot,
                                              const float* __restrict__ fw,
                                              const float* __restrict__ fb,
                                              float* __restrict__ xc, int N) {
    __shared__ float red[4][32];
    __shared__ float pv[32];
    int g = blockIdx.x, t = threadIdx.x;
    int lo = lbound(batch, N, g);
    int hi = lbound(batch, N, g + 1);
    int j = t & 31, rs = t >> 5;
    float ps = 0.f;
    for (int i = lo + rs; i < hi; i += 4) ps += X[(size_t)i * 32 + j];
    red[rs][j] = ps; __syncthreads();
    if (t < 32) {
        float s = red[0][t] + red[1][t] + red[2][t] + red[3][t];
        pv[t] = s * slot[512 + t] + (float)(hi - lo) * slot[544 + t];
    }
    __syncthreads();
    float acc = fb[t];
    for (int k = 0; k < 32; k++) acc += pv[k] * fw[k * 128 + t];
    xc[g * 256 + t] = fmaxf(acc, 0.f);
}

// ---------------- protein branch ----------------
// per (v,o): all 8 k-offsets in one pass over the o-slice of fcxt
__global__ void __launch_bounds__(128) k_F2(const float* __restrict__ Emb,
                                            const float* __restrict__ fcxt,
                                            float* __restrict__ F) {
    __shared__ float er[128];
    int bid = blockIdx.x;
    int v = bid >> 5, o = bid & 31;
    int t = threadIdx.x;
    er[t] = Emb[v * 128 + t];
    __syncthreads();
    float acc[8] = {0.f, 0.f, 0.f, 0.f, 0.f, 0.f, 0.f, 0.f};
    for (int p = 0; p < 121; p++) {
        float fv = fcxt[(o * 121 + p) * 128 + t];
        #pragma unroll
        for (int k = 0; k < 8; k++) acc[k] += er[p + k] * fv;
    }
    #pragma unroll
    for (int k = 0; k < 8; k++)
        F[((size_t)v * 256 + o * 8 + k) * 128 + t] = acc[k];
}

__global__ void __launch_bounds__(128) k_cb(const float* __restrict__ fcxt,
                                            const float* __restrict__ fb,
                                            const float* __restrict__ cb,
                                            float* __restrict__ cbias) {
    int o = blockIdx.x, t = threadIdx.x;
    float acc = 0.f;
    for (int p = 0; p < 121; p++) acc += fcxt[(o * 121 + p) * 128 + t];
    float val = cb[o] * acc;
    if (o == 0) val += fb[t];
    atomicAdd(&cbias[t], val);
}

// transpose conv_w [o][c][k] -> wt[ok=o*8+k][c]
__global__ void __launch_bounds__(256) k_wT(const float* __restrict__ cw,
                                            float* __restrict__ wt) {
    int ok = blockIdx.x;
    int o = ok >> 3, kk = ok & 7;
    for (int c = threadIdx.x; c < 1000; c += 256)
        wt[ok * 1000 + c] = cw[(o * 1000 + c) * 8 + kk];
}

// Dm_bf[c][v][j-pairs] = bf16( sum_ok wt[ok][c] * F[v][ok][j] )
__global__ void __launch_bounds__(256) k_D2(const float* __restrict__ wt,
                                            const float* __restrict__ F,
                                            unsigned* __restrict__ Dmb) {
    __shared__ float Fl[32][128];
    __shared__ float Wl[32][64];
    int v = blockIdx.y;
    int c0 = blockIdx.x * 64;
    int t = threadIdx.x;
    int jg = t & 31, j0 = jg * 4;
    int cg = t >> 5;
    float4 acc[8];
    #pragma unroll
    for (int i = 0; i < 8; i++) acc[i] = make_float4(0.f, 0.f, 0.f, 0.f);
    for (int chunk = 0; chunk < 8; chunk++) {
        int k0 = chunk * 32;
        __syncthreads();
        for (int idx = t; idx < 4096; idx += 256) {
            int k = idx >> 7, j = idx & 127;
            Fl[k][j] = F[((size_t)v * 256 + k0 + k) * 128 + j];
        }
        for (int idx = t; idx < 2048; idx += 256) {
            int k = idx >> 6, c = idx & 63;
            Wl[k][c] = (c0 + c < 1000) ? wt[(k0 + k) * 1000 + c0 + c] : 0.f;
        }
        __syncthreads();
        for (int k = 0; k < 32; k++) {
            float4 fv = *(const float4*)&Fl[k][j0];
            #pragma unroll
            for (int ci = 0; ci < 8; ci++) {
                float wv = Wl[k][cg * 8 + ci];
                acc[ci].x += wv * fv.x;
                acc[ci].y += wv * fv.y;
                acc[ci].z += wv * fv.z;
                acc[ci].w += wv * fv.w;
            }
        }
    }
    #pragma unroll
    for (int ci = 0; ci < 8; ci++) {
        int c = c0 + cg * 8 + ci;
        if (c < 1000) {
            uint2 pk;
            pk.x = packbf2(acc[ci].x, acc[ci].y);
            pk.y = packbf2(acc[ci].z, acc[ci].w);
            *(uint2*)&Dmb[((size_t)c * 26 + v) * 64 + jg * 2] = pk;
        }
    }
}

// xt: one block per graph; 16 c-lanes x 16 j-lanes; no atomics
__global__ void __launch_bounds__(256) k_xt3(const int* __restrict__ target,
                                             const uint4* __restrict__ Dm4,
                                             const float* __restrict__ cbias,
                                             float* __restrict__ xc) {
    __shared__ int tl[1000];
    __shared__ float red[16][132];
    int b = blockIdx.x, t = threadIdx.x;
    for (int i = t; i < 1000; i += 256) tl[i] = target[(size_t)b * 1000 + i];
    __syncthreads();
    int cl = t >> 4;            // 16 c-lanes
    int jg = t & 15;            // 16 j-groups (uint4 = 8 features each)
    float acc[8] = {0.f, 0.f, 0.f, 0.f, 0.f, 0.f, 0.f, 0.f};
    for (int c = cl; c < 1000; c += 16) {
        int v = tl[c];
        uint4 d = Dm4[((size_t)c * 26 + v) * 16 + jg];
        acc[0] += lo_bf(d.x); acc[1] += hi_bf(d.x);
        acc[2] += lo_bf(d.y); acc[3] += hi_bf(d.y);
        acc[4] += lo_bf(d.z); acc[5] += hi_bf(d.z);
        acc[6] += lo_bf(d.w); acc[7] += hi_bf(d.w);
    }
    #pragma unroll
    for (int fi = 0; fi < 8; fi++) red[cl][jg * 8 + fi] = acc[fi];
    __syncthreads();
    if (t < 128) {
        float s = 0.f;
        #pragma unroll
        for (int r = 0; r < 16; r++) s += red[r][t];
        xc[(size_t)b * 256 + 128 + t] = cbias[t] + s;
    }
}

// ---------------- head ----------------
__global__ void __launch_bounds__(256) k_fc1(const float* __restrict__ xc,
                                             const float* __restrict__ w,
                                             const float* __restrict__ bias,
                                             float* __restrict__ y1) {
    __shared__ float xl[16 * 256];
    int t = threadIdx.x;
    int q0 = blockIdx.x * 256, b0 = blockIdx.y * 16;
    for (int idx = t; idx < 4096; idx += 256) xl[idx] = xc[b0 * 256 + idx];
    __syncthreads();
    int ql = t & 63, q = q0 + ql * 4;
    int bg = t >> 6;
    float4 bv = *(const float4*)&bias[q];
    float4 acc0 = bv, acc1 = bv, acc2 = bv, acc3 = bv;
    const float* xr = &xl[bg * 4 * 256];
    #pragma unroll 4
    for (int k = 0; k < 256; k++) {
        float4 wv = *(const float4*)&w[k * 1024 + q];
        float x0 = xr[k], x1 = xr[256 + k], x2 = xr[512 + k], x3 = xr[768 + k];
        acc0.x += x0 * wv.x; acc0.y += x0 * wv.y; acc0.z += x0 * wv.z; acc0.w += x0 * wv.w;
        acc1.x += x1 * wv.x; acc1.y += x1 * wv.y; acc1.z += x1 * wv.z; acc1.w += x1 * wv.w;
        acc2.x += x2 * wv.x; acc2.y += x2 * wv.y; acc2.z += x2 * wv.z; acc2.w += x2 * wv.w;
        acc3.x += x3 * wv.x; acc3.y += x3 * wv.y; acc3.z += x3 * wv.z; acc3.w += x3 * wv.w;
    }
    int b = b0 + bg * 4;
    float4 r;
    r.x = fmaxf(acc0.x, 0.f); r.y = fmaxf(acc0.y, 0.f); r.z = fmaxf(acc0.z, 0.f); r.w = fmaxf(acc0.w, 0.f);
    *(float4*)&y1[(size_t)b * 1024 + q] = r;
    r.x = fmaxf(acc1.x, 0.f); r.y = fmaxf(acc1.y, 0.f); r.z = fmaxf(acc1.z, 0.f); r.w = fmaxf(acc1.w, 0.f);
    *(float4*)&y1[(size_t)(b + 1) * 1024 + q] = r;
    r.x = fmaxf(acc2.x, 0.f); r.y = fmaxf(acc2.y, 0.f); r.z = fmaxf(acc2.z, 0.f); r.w = fmaxf(acc2.w, 0.f);
    *(float4*)&y1[(size_t)(b + 2) * 1024 + q] = r;
    r.x = fmaxf(acc3.x, 0.f); r.y = fmaxf(acc3.y, 0.f); r.z = fmaxf(acc3.z, 0.f); r.w = fmaxf(acc3.w, 0.f);
    *(float4*)&y1[(size_t)(b + 3) * 1024 + q] = r;
}

__global__ void k_wcomb(const float* __restrict__ fc2w, const float* __restrict__ fc2b,
                        const float* __restrict__ ow, const float* __restrict__ ob,
                        float* __restrict__ wc) {
    int p = blockIdx.x * 256 + threadIdx.x;
    float acc = 0.f;
    for (int q = 0; q < 256; q++) acc += fc2w[p * 256 + q] * ow[q];
    wc[p] = acc;
    if (p == 0) {
        float bc = ob[0];
        for (int q = 0; q < 256; q++) bc += fc2b[q] * ow[q];
        wc[1024] = bc;
    }
}

__global__ void __launch_bounds__(256) k_out(const float* __restrict__ y1,
                                             const float* __restrict__ wc,
                                             float* __restrict__ out) {
    __shared__ float r[256];
    int b = blockIdx.x, t = threadIdx.x;
    float acc = 0.f;
    for (int p = t; p < 1024; p += 256) acc += y1[b * 1024 + p] * wc[p];
    r[t] = acc; __syncthreads();
    for (int off = 128; off > 0; off >>= 1) {
        if (t < off) r[t] += r[t + off];
        __syncthreads();
    }
    if (t == 0) out[b] = r[0] + wc[1024];
}

extern "C" void kernel_launch(void* const* d_in, const int* in_sizes, int n_in,
                              void* d_out, int out_size, void* d_ws, size_t ws_size,
                              hipStream_t stream) {
    const float* x     = (const float*)d_in[0];
    const int*   ei    = (const int*)d_in[1];
    const int*   batch = (const int*)d_in[2];
    const int*   targ  = (const int*)d_in[3];
    const float* g1w1  = (const float*)d_in[4];
    const float* g1b1  = (const float*)d_in[5];
    const float* g1w2  = (const float*)d_in[6];
    const float* g1b2  = (const float*)d_in[7];
    const float* gW1   = (const float*)d_in[8];
    const float* gb1   = (const float*)d_in[9];
    const float* gW2   = (const float*)d_in[10];
    const float* gb2   = (const float*)d_in[11];
    const float* gam   = (const float*)d_in[12];
    const float* bet   = (const float*)d_in[13];
    const float* fcxdw = (const float*)d_in[14];
    const float* fcxdb = (const float*)d_in[15];
    const float* emb   = (const float*)d_in[16];
    const float* convw = (const float*)d_in[17];
    const float* convb = (const float*)d_in[18];
    const float* fcxtw = (const float*)d_in[19];
    const float* fcxtb = (const float*)d_in[20];
    const float* fc1w  = (const float*)d_in[21];
    const float* fc1b  = (const float*)d_in[22];
    const float* fc2w  = (const float*)d_in[23];
    const float* fc2b  = (const float*)d_in[24];
    const float* outw  = (const float*)d_in[25];
    const float* outb  = (const float*)d_in[26];

    int N = in_sizes[2];
    int E = in_sizes[1] / 2;
    int B = in_sizes[3] / 1000;
    int NB = (N + 511) >> BSHIFT;

    char* ws = (char*)d_ws;
    size_t off = 0;
    auto alloc = [&](size_t bytes) -> void* {
        void* p = ws + off;
        off += (bytes + 255) & ~(size_t)255;
        return p;
    };
    int*   rowstart = (int*)alloc((size_t)(N + 1) * 4);
    int*   bbase    = (int*)alloc((NBMAX + 1) * 4);
    int*   gcur     = (int*)alloc(NBMAX * 4);
    int*   csr      = (int*)alloc((size_t)E * 4);
    // pairs (NB*FSTRIDE*4 = 16 MB) aliases X (N*32*4 = 25.6 MB): pairs dead before first X write
    float* X        = (float*)alloc((size_t)N * 32 * 4);
    int*   pairs    = (int*)X;
    unsigned* Ub    = (unsigned*)alloc((size_t)N * 16 * 4);
    float* stats    = (float*)alloc((size_t)5 * 640 * 4);
    float* xc       = (float*)alloc((size_t)B * 256 * 4);
    float* Fb       = (float*)alloc((size_t)26 * 256 * 128 * 4);
    unsigned* Dmb   = (unsigned*)alloc((size_t)1000 * 26 * 64 * 4);
    float* wt       = (float*)alloc((size_t)256 * 1000 * 4);
    float* cbias    = (float*)alloc(128 * 4);
    float* y1       = (float*)alloc((size_t)B * 1024 * 4);
    float* wc       = (float*)alloc(1025 * 4);

    hipMemsetAsync(gcur, 0, NBMAX * 4, stream);
    hipMemsetAsync(stats, 0, (size_t)5 * 640 * 4, stream);
    hipMemsetAsync(cbias, 0, 128 * 4, stream);

    // CSR build
    k_bscatter<<<(E + SCAT_CH - 1) / SCAT_CH, 256, 0, stream>>>(ei, gcur, pairs, E, NB);
    k_bscan<<<1, 512, 0, stream>>>(gcur, bbase, rowstart, N, E, NB);
    k_bfinal<<<NB, 512, 0, stream>>>(pairs, bbase, gcur, rowstart, csr, N);

    // layer 1
    k_A1<<<(N + 63) / 64, 256, 0, stream>>>(x, g1w1, Ub, N);
    k_BCS<<<(N + 63) / 64, 256, 0, stream>>>((const uint4*)Ub, rowstart, csr,
                                             g1b1, g1w2, g1b2, X, stats, N);
    k_fin<<<1, 32, 0, stream>>>(stats, gam, bet, N);

    // layers 2..5
    for (int i = 0; i < 4; i++) {
        float* slotPrev = stats + (size_t)i * 640;
        float* slotCur  = stats + (size_t)(i + 1) * 640;
        k_A<<<(N + 127) / 128, 256, 0, stream>>>(X, gW1 + i * 1024, slotPrev, Ub, N);
        k_BCS<<<(N + 63) / 64, 256, 0, stream>>>((const uint4*)Ub, rowstart, csr,
                                                 gb1 + i * 32, gW2 + i * 1024,
                                                 gb2 + i * 32, X, slotCur, N);
        k_fin<<<1, 32, 0, stream>>>(slotCur, gam + (i + 1) * 32, bet + (i + 1) * 32, N);
    }

    // pooling + xd -> xc[:, 0:128]
    k_pool<<<B, 128, 0, stream>>>(X, batch, stats + 4 * 640, fcxdw, fcxdb, xc, N);

    // protein branch -> xc[:, 128:256]
    k_wT<<<256, 256, 0, stream>>>(convw, wt);
    k_F2<<<26 * 32, 128, 0, stream>>>(emb, fcxtw, Fb);
    k_cb<<<32, 128, 0, stream>>>(fcxtw, fcxtb, convb, cbias);
    dim3 gD(16, 26);
    k_D2<<<gD, 256, 0, stream>>>(wt, Fb, Dmb);
    k_xt3<<<B, 256, 0, stream>>>(targ, (const uint4*)Dmb, cbias, xc);

    // head
    dim3 g1(4, B / 16);
    k_fc1<<<g1, 256, 0, stream>>>(xc, fc1w, fc1b, y1);
    k_wcomb<<<4, 256, 0, stream>>>(fc2w, fc2b, outw, outb, wc);
    k_out<<<B, 256, 0, stream>>>(y1, wc, (float*)d_out);
}